// Round 2
// baseline (661.844 us; speedup 1.0000x reference)
//
#include <hip/hip_runtime.h>
#include <hip/hip_bf16.h>

typedef short short8 __attribute__((ext_vector_type(8)));
typedef float f32x4  __attribute__((ext_vector_type(4)));

#define EMB   512
#define MEM   128
#define G3    384
#define CLS_K (EMB + MEM)   // 640
#define BR    32            // rows per block
#define NTHR  256

__device__ __forceinline__ short f2b(float f) {
  unsigned u = __float_as_uint(f);
  u += 0x7fffu + ((u >> 16) & 1u);          // RNE; inputs are finite
  return (short)(u >> 16);
}
__device__ __forceinline__ float sigm(float x)     { return 1.f / (1.f + __expf(-x)); }
__device__ __forceinline__ float tanhfast(float x) { return 2.f / (1.f + __expf(-2.f * x)) - 1.f; }

// ---- convert W_ih / W_hh / W_cls to bf16 in workspace ----
__global__ void prep_w_kernel(const float* __restrict__ wih, const float* __restrict__ whh,
                              const float* __restrict__ wcls, short* __restrict__ outw) {
  int i = blockIdx.x * blockDim.x + threadIdx.x;
  const int n1 = G3 * EMB;
  const int n2 = n1 + G3 * MEM;
  const int n3 = n2 + 2 * CLS_K;
  if (i < n1) outw[i] = f2b(wih[i]);
  else if (i < n2) outw[i] = f2b(whh[i - n1]);
  else if (i < n3) outw[i] = f2b(wcls[i - n2]);
}

// ---- full bank copy (fused kernel's scatter overwrites active rows later) ----
__global__ void copy_bank_kernel(const f32x4* __restrict__ src, f32x4* __restrict__ dst, int n4) {
  int i = blockIdx.x * blockDim.x + threadIdx.x;
  int stride = gridDim.x * blockDim.x;
  for (; i < n4; i += stride) dst[i] = src[i];
}

// load 8 f32 and convert to a bf16 MFMA fragment
__device__ __forceinline__ short8 loadA(const float* __restrict__ p) {
  f32x4 a = *(const f32x4*)p;
  f32x4 b = *(const f32x4*)(p + 4);
  short8 v;
  v[0] = f2b(a[0]); v[1] = f2b(a[1]); v[2] = f2b(a[2]); v[3] = f2b(a[3]);
  v[4] = f2b(b[0]); v[5] = f2b(b[1]); v[6] = f2b(b[2]); v[7] = f2b(b[3]);
  return v;
}

template <bool BF16W>
__device__ __forceinline__ short8 loadW(const short* __restrict__ wb,
                                        const float* __restrict__ wf, size_t off) {
  if constexpr (BF16W) {
    return *(const short8*)(wb + off);
  } else {
    f32x4 a = *(const f32x4*)(wf + off);
    f32x4 b = *(const f32x4*)(wf + off + 4);
    short8 v;
    v[0] = f2b(a[0]); v[1] = f2b(a[1]); v[2] = f2b(a[2]); v[3] = f2b(a[3]);
    v[4] = f2b(b[0]); v[5] = f2b(b[1]); v[6] = f2b(b[2]); v[7] = f2b(b[3]);
    return v;
  }
}

template <bool BF16W>
__global__ __launch_bounds__(NTHR, 3)
void fused_gru_kernel(const float* __restrict__ emb, const int* __restrict__ ids,
                      const float* __restrict__ bank,
                      const float* __restrict__ Wihf, const float* __restrict__ Whhf,
                      const float* __restrict__ bih,  const float* __restrict__ bhh,
                      const float* __restrict__ Wcls, const float* __restrict__ bcls,
                      const short* __restrict__ Wb,
                      float* __restrict__ out_logits, float* __restrict__ out_bank, int N) {
  __shared__ float sLP[4][BR][2];   // per-m-slice mem-part logit partials
  __shared__ float sLE[BR][2];      // emb-part logits (from wave 0's MFMA)

  const int t  = threadIdx.x;
  const int w  = t >> 6;            // m-slice 0..3
  const int l  = t & 63;
  const int lr = l & 15;
  const int lk = l >> 4;
  const int r0 = blockIdx.x * BR;
  const int mb = w * 32;

  int grow0 = r0 + lr;      if (grow0 > N - 1) grow0 = N - 1;
  int grow1 = r0 + 16 + lr; if (grow1 > N - 1) grow1 = N - 1;
  const int gid0 = ids[grow0];
  const int gid1 = ids[grow1];

  const float* x0 = emb  + (size_t)grow0 * EMB + lk * 8;
  const float* x1 = emb  + (size_t)grow1 * EMB + lk * 8;
  const float* h0 = bank + (size_t)gid0 * MEM + lk * 8;
  const float* h1 = bank + (size_t)gid1 * MEM + lk * 8;

  const short* Wihb  = Wb;
  const short* Whhb  = Wb + G3 * EMB;
  const short* Wclsb = Wb + G3 * EMB + G3 * MEM;

  f32x4 acc[2][2][3];   // [rowtile][mtile][gate] gate0=r(i+h), gate1=z(i+h), gate2=i_n
  f32x4 accN[2][2];     // h_n
  f32x4 accL[2];        // emb-part logits (only wave 0 meaningful)
  const f32x4 zero = {0.f, 0.f, 0.f, 0.f};
#pragma unroll
  for (int rt = 0; rt < 2; ++rt) {
#pragma unroll
    for (int mt = 0; mt < 2; ++mt) {
#pragma unroll
      for (int g = 0; g < 3; ++g) acc[rt][mt][g] = zero;
      accN[rt][mt] = zero;
    }
    accL[rt] = zero;
  }

  // ---------------- GEMM1: X @ W_ih^T  (+ W_cls emb-part on wave 0) ----------------
  for (int kc = 0; kc < EMB / 32; ++kc) {
    const int k0 = kc * 32;
    const short8 a0 = loadA(x0 + k0);
    const short8 a1 = loadA(x1 + k0);
#pragma unroll
    for (int g = 0; g < 3; ++g)
#pragma unroll
      for (int mt = 0; mt < 2; ++mt) {
        const int c = g * MEM + mb + mt * 16 + lr;
        const short8 bq = loadW<BF16W>(Wihb, Wihf, (size_t)c * EMB + k0 + lk * 8);
        acc[0][mt][g] = __builtin_amdgcn_mfma_f32_16x16x32_bf16(a0, bq, acc[0][mt][g], 0, 0, 0);
        acc[1][mt][g] = __builtin_amdgcn_mfma_f32_16x16x32_bf16(a1, bq, acc[1][mt][g], 0, 0, 0);
      }
    if (w == 0) {
      short8 bqL = {0, 0, 0, 0, 0, 0, 0, 0};
      if (lr < 2) bqL = loadW<BF16W>(Wclsb, Wcls, (size_t)lr * CLS_K + k0 + lk * 8);
      accL[0] = __builtin_amdgcn_mfma_f32_16x16x32_bf16(a0, bqL, accL[0], 0, 0, 0);
      accL[1] = __builtin_amdgcn_mfma_f32_16x16x32_bf16(a1, bqL, accL[1], 0, 0, 0);
    }
  }

  // ---------------- GEMM2: H @ W_hh^T  (r,z fold into acc; n-part into accN) -------
  for (int kc = 0; kc < MEM / 32; ++kc) {
    const int k0 = kc * 32;
    const short8 a0 = loadA(h0 + k0);
    const short8 a1 = loadA(h1 + k0);
#pragma unroll
    for (int mt = 0; mt < 2; ++mt) {
      const int cb = mb + mt * 16 + lr;
      const short8 b0 = loadW<BF16W>(Whhb, Whhf, (size_t)cb * MEM + k0 + lk * 8);
      const short8 b1 = loadW<BF16W>(Whhb, Whhf, (size_t)(MEM + cb) * MEM + k0 + lk * 8);
      const short8 b2 = loadW<BF16W>(Whhb, Whhf, (size_t)(2 * MEM + cb) * MEM + k0 + lk * 8);
      acc[0][mt][0] = __builtin_amdgcn_mfma_f32_16x16x32_bf16(a0, b0, acc[0][mt][0], 0, 0, 0);
      acc[1][mt][0] = __builtin_amdgcn_mfma_f32_16x16x32_bf16(a1, b0, acc[1][mt][0], 0, 0, 0);
      acc[0][mt][1] = __builtin_amdgcn_mfma_f32_16x16x32_bf16(a0, b1, acc[0][mt][1], 0, 0, 0);
      acc[1][mt][1] = __builtin_amdgcn_mfma_f32_16x16x32_bf16(a1, b1, acc[1][mt][1], 0, 0, 0);
      accN[0][mt]   = __builtin_amdgcn_mfma_f32_16x16x32_bf16(a0, b2, accN[0][mt],   0, 0, 0);
      accN[1][mt]   = __builtin_amdgcn_mfma_f32_16x16x32_bf16(a1, b2, accN[1][mt],   0, 0, 0);
    }
  }

  // ---------------- GRU epilogue + scatter + logits mem-part ----------------
#pragma unroll
  for (int rt = 0; rt < 2; ++rt) {
#pragma unroll
    for (int j = 0; j < 4; ++j) {
      const int rowl = rt * 16 + lk * 4 + j;    // C/D: row=(lane>>4)*4+reg, col=lane&15
      const int grow = r0 + rowl;
      const bool valid = grow < N;
      const int gid = ids[valid ? grow : N - 1];
      float lp0 = 0.f, lp1 = 0.f;
#pragma unroll
      for (int mt = 0; mt < 2; ++mt) {
        const int m = mb + mt * 16 + lr;
        const float rg = sigm(acc[rt][mt][0][j] + bih[m] + bhh[m]);
        const float zg = sigm(acc[rt][mt][1][j] + bih[MEM + m] + bhh[MEM + m]);
        const float hn = accN[rt][mt][j] + bhh[2 * MEM + m];
        const float ng = tanhfast(acc[rt][mt][2][j] + bih[2 * MEM + m] + rg * hn);
        const float hp = bank[(size_t)gid * MEM + m];
        const float nv = (1.f - zg) * ng + zg * hp;
        if (valid) out_bank[(size_t)gid * MEM + m] = nv;
        lp0 += nv * Wcls[EMB + m];
        lp1 += nv * Wcls[CLS_K + EMB + m];
      }
#pragma unroll
      for (int s = 1; s < 16; s <<= 1) {
        lp0 += __shfl_xor(lp0, s);
        lp1 += __shfl_xor(lp1, s);
      }
      if (lr == 0) { sLP[w][rowl][0] = lp0; sLP[w][rowl][1] = lp1; }
      if (w == 0 && lr < 2) sLE[rowl][lr] = accL[rt][j];
    }
  }
  __syncthreads();

  if (t < BR * 2) {
    const int row = t >> 1, c = t & 1;
    const int grow = r0 + row;
    if (grow < N) {
      out_logits[(size_t)grow * 2 + c] =
          sLE[row][c] + sLP[0][row][c] + sLP[1][row][c] + sLP[2][row][c] + sLP[3][row][c] + bcls[c];
    }
  }
}

extern "C" void kernel_launch(void* const* d_in, const int* in_sizes, int n_in,
                              void* d_out, int out_size, void* d_ws, size_t ws_size,
                              hipStream_t stream) {
  const float* emb  = (const float*)d_in[0];
  const int*   ids  = (const int*)d_in[1];
  const float* bank = (const float*)d_in[2];
  const float* wih  = (const float*)d_in[3];
  const float* whh  = (const float*)d_in[4];
  const float* bih  = (const float*)d_in[5];
  const float* bhh  = (const float*)d_in[6];
  const float* wcls = (const float*)d_in[7];
  const float* bcls = (const float*)d_in[8];

  const int N          = in_sizes[1];
  const int bank_elems = in_sizes[2];

  float* out_logits = (float*)d_out;
  float* out_bank   = (float*)d_out + (size_t)N * 2;

  // 1) copy whole bank to output (scatter overwrites active rows later)
  const int n4 = bank_elems / 4;
  copy_bank_kernel<<<8192, 256, 0, stream>>>((const f32x4*)bank, (f32x4*)out_bank, n4);

  const int nb = (N + BR - 1) / BR;
  const int wtot = G3 * EMB + G3 * MEM + 2 * CLS_K;
  const size_t wbytes = (size_t)wtot * sizeof(short);
  if (ws_size >= wbytes) {
    short* wb = (short*)d_ws;
    prep_w_kernel<<<(wtot + 255) / 256, 256, 0, stream>>>(wih, whh, wcls, wb);
    fused_gru_kernel<true><<<nb, NTHR, 0, stream>>>(emb, ids, bank, wih, whh, bih, bhh,
                                                    wcls, bcls, wb, out_logits, out_bank, N);
  } else {
    fused_gru_kernel<false><<<nb, NTHR, 0, stream>>>(emb, ids, bank, wih, whh, bih, bhh,
                                                     wcls, bcls, nullptr, out_logits, out_bank, N);
  }
}

// Round 3
// 462.733 us; speedup vs baseline: 1.4303x; 1.4303x over previous
//
#include <hip/hip_runtime.h>
#include <hip/hip_bf16.h>

typedef short short8 __attribute__((ext_vector_type(8)));
typedef float f32x4  __attribute__((ext_vector_type(4)));
typedef unsigned int u32;

#define EMB   512
#define MEM   128
#define G3    384
#define CLS_K 640
#define MSPLIT 4
#define MSL   32              // m-columns per block
#define BR    256             // rows per block (8 waves x 32)
#define NTHR  512

#define W1ROWS 96             // 3 gates * MSL
#define SWIH_E (W1ROWS * EMB) // 49152 shorts
#define SWHH_E (W1ROWS * MEM) // 12288 shorts
#define SWCL_E (2 * EMB)      // 1024 shorts

__device__ __forceinline__ short f2b(float f) {
  __hip_bfloat16 h = __float2bfloat16(f);
  return __builtin_bit_cast(short, h);
}
__device__ __forceinline__ short8 cvt8(f32x4 a, f32x4 b) {
  short8 v;
  v[0] = f2b(a[0]); v[1] = f2b(a[1]); v[2] = f2b(a[2]); v[3] = f2b(a[3]);
  v[4] = f2b(b[0]); v[5] = f2b(b[1]); v[6] = f2b(b[2]); v[7] = f2b(b[3]);
  return v;
}
__device__ __forceinline__ float sigm(float x)     { return 1.f / (1.f + __expf(-x)); }
__device__ __forceinline__ float tanhfast(float x) { return 2.f / (1.f + __expf(-2.f * x)) - 1.f; }

// swizzled LDS access: spreads same-column reads across 8 16B slots
__device__ __forceinline__ short8 ldsW(const short* base, int rowBytes, int r, int kb) {
  const int byte = (r * rowBytes + kb) ^ ((r & 7) << 4);
  return *(const short8*)((const char*)base + byte);
}
__device__ __forceinline__ void stsW(short* base, int rowBytes, int r, int kb, short8 v) {
  const int byte = (r * rowBytes + kb) ^ ((r & 7) << 4);
  *(short8*)((char*)base + byte) = v;
}

// ---- convert all weights to bf16 in workspace ----
__global__ void prep_w_kernel(const float* __restrict__ wih, const float* __restrict__ whh,
                              const float* __restrict__ wcls, short* __restrict__ outw) {
  int i = blockIdx.x * blockDim.x + threadIdx.x;
  const int n1 = G3 * EMB;
  const int n2 = n1 + G3 * MEM;
  const int n3 = n2 + 2 * CLS_K;
  if (i < n1) outw[i] = f2b(wih[i]);
  else if (i < n2) outw[i] = f2b(whh[i - n1]);
  else if (i < n3) outw[i] = f2b(wcls[i - n2]);
}

// ---- zero logits + bitmap ----
__global__ void zero_kernel(float* __restrict__ lg, int nlg, u32* __restrict__ bm, int nbm) {
  int i = blockIdx.x * blockDim.x + threadIdx.x;
  int stride = gridDim.x * blockDim.x;
  for (; i < nlg + nbm; i += stride) {
    if (i < nlg) lg[i] = 0.f;
    else if (bm) bm[i - nlg] = 0u;
  }
}

__global__ void bitmap_set_kernel(const int* __restrict__ ids, unsigned char* __restrict__ bm, int n) {
  int i = blockIdx.x * blockDim.x + threadIdx.x;
  if (i < n) bm[ids[i]] = 1;
}

// ---- bank copy; skips rows the scatter will overwrite (bm!=null) ----
__global__ void copy_bank_kernel(const f32x4* __restrict__ src, f32x4* __restrict__ dst,
                                 const unsigned char* __restrict__ bm, int n4) {
  int i = blockIdx.x * blockDim.x + threadIdx.x;
  int stride = gridDim.x * blockDim.x;
  for (; i < n4; i += stride) {
    if (bm && bm[i >> 5]) continue;    // MEM/4 = 32 chunks per row
    dst[i] = src[i];
  }
}

template <bool BF16W>
__global__ __launch_bounds__(NTHR, 2)
void fused_gru_kernel(const float* __restrict__ emb, const int* __restrict__ ids,
                      const float* __restrict__ bank,
                      const float* __restrict__ Wihf, const float* __restrict__ Whhf,
                      const float* __restrict__ bih,  const float* __restrict__ bhh,
                      const float* __restrict__ Wcls, const float* __restrict__ bcls,
                      const short* __restrict__ Wb,
                      float* __restrict__ out_logits, float* __restrict__ out_bank, int N) {
  __shared__ __align__(16) short sW[SWIH_E + SWHH_E + SWCL_E];   // 122 KB
  short* sWih = sW;
  short* sWhh = sW + SWIH_E;
  short* sWcl = sW + SWIH_E + SWHH_E;

  const int t  = threadIdx.x;
  const int ms = blockIdx.x & (MSPLIT - 1);       // m-slice 0..3
  const int rb = blockIdx.x >> 2;                 // row block
  const bool ms0 = (ms == 0);
  const int r0 = rb * BR;

  const short* Wihb = Wb;
  const short* Whhb = Wb + G3 * EMB;
  const short* Wclb = Wb + G3 * EMB + G3 * MEM;

  // ---------------- stage weight slices into swizzled LDS ----------------
  // local row r in [0,96): gate g=r/32, mloc=r%32 -> global row g*128 + ms*32 + mloc
#pragma unroll
  for (int i = 0; i < 12; ++i) {                    // W_ih: 6144 16B chunks
    const int c = t + i * NTHR;
    const int r = c >> 6, k8 = c & 63;
    const int grow = (r >> 5) * MEM + ms * MSL + (r & 31);
    short8 v;
    if constexpr (BF16W) v = *(const short8*)(Wihb + (size_t)grow * EMB + k8 * 8);
    else {
      const float* p = Wihf + (size_t)grow * EMB + k8 * 8;
      v = cvt8(*(const f32x4*)p, *(const f32x4*)(p + 4));
    }
    stsW(sWih, EMB * 2, r, k8 * 16, v);
  }
#pragma unroll
  for (int i = 0; i < 3; ++i) {                     // W_hh: 1536 16B chunks
    const int c = t + i * NTHR;
    const int r = c >> 4, k8 = c & 15;
    const int grow = (r >> 5) * MEM + ms * MSL + (r & 31);
    short8 v;
    if constexpr (BF16W) v = *(const short8*)(Whhb + (size_t)grow * MEM + k8 * 8);
    else {
      const float* p = Whhf + (size_t)grow * MEM + k8 * 8;
      v = cvt8(*(const f32x4*)p, *(const f32x4*)(p + 4));
    }
    stsW(sWhh, MEM * 2, r, k8 * 16, v);
  }
  if (t < 128) {                                    // W_cls emb-part: 2 rows x 512
    const int r = t >> 6, k8 = t & 63;
    short8 v;
    if constexpr (BF16W) v = *(const short8*)(Wclb + (size_t)r * CLS_K + k8 * 8);
    else {
      const float* p = Wcls + (size_t)r * CLS_K + k8 * 8;
      v = cvt8(*(const f32x4*)p, *(const f32x4*)(p + 4));
    }
    stsW(sWcl, EMB * 2, r, k8 * 16, v);
  }
  __syncthreads();

  // ---------------- per-wave setup ----------------
  const int w    = t >> 6;          // 0..7, wave owns rows [w*32, w*32+32)
  const int l    = t & 63;
  const int lr   = l & 15;
  const int lk   = l >> 4;
  const int wrow = w * 32;

  int grow0 = r0 + wrow + lr;      if (grow0 > N - 1) grow0 = N - 1;
  int grow1 = r0 + wrow + 16 + lr; if (grow1 > N - 1) grow1 = N - 1;
  const int gid0 = ids[grow0];
  const int gid1 = ids[grow1];

  const float* x0 = emb  + (size_t)grow0 * EMB + lk * 8;
  const float* x1 = emb  + (size_t)grow1 * EMB + lk * 8;
  const float* h0 = bank + (size_t)gid0 * MEM + lk * 8;
  const float* h1 = bank + (size_t)gid1 * MEM + lk * 8;

  f32x4 acc[2][2][3];   // [rowtile][mtile][gate0=r, gate1=z, gate2=i_n]
  f32x4 accN[2][2];     // h_n
  f32x4 accL[2];        // emb-part logits (ms==0 only)
  const f32x4 zero = {0.f, 0.f, 0.f, 0.f};
#pragma unroll
  for (int rt = 0; rt < 2; ++rt) {
#pragma unroll
    for (int mt = 0; mt < 2; ++mt) {
#pragma unroll
      for (int g = 0; g < 3; ++g) acc[rt][mt][g] = zero;
      accN[rt][mt] = zero;
    }
    accL[rt] = zero;
  }

  // issue GEMM2's first A-loads early (gathered; hide latency under GEMM1)
  f32x4 qa0 = *(const f32x4*)h0, qb0 = *(const f32x4*)(h0 + 4);
  f32x4 qa1 = *(const f32x4*)h1, qb1 = *(const f32x4*)(h1 + 4);

  // ---------------- GEMM1: X @ W_ih^T (B from LDS, A prefetched) ----------------
  f32x4 pa0 = *(const f32x4*)x0, pb0 = *(const f32x4*)(x0 + 4);
  f32x4 pa1 = *(const f32x4*)x1, pb1 = *(const f32x4*)(x1 + 4);
#pragma unroll 4
  for (int kc = 0; kc < EMB / 32; ++kc) {
    const int kn = (kc < EMB / 32 - 1) ? kc + 1 : kc;
    f32x4 na0 = *(const f32x4*)(x0 + kn * 32), nb0 = *(const f32x4*)(x0 + kn * 32 + 4);
    f32x4 na1 = *(const f32x4*)(x1 + kn * 32), nb1 = *(const f32x4*)(x1 + kn * 32 + 4);
    const short8 a0 = cvt8(pa0, pb0);
    const short8 a1 = cvt8(pa1, pb1);
    const int kb = (kc * 32 + lk * 8) * 2;
#pragma unroll
    for (int g = 0; g < 3; ++g)
#pragma unroll
      for (int mt = 0; mt < 2; ++mt) {
        const short8 bq = ldsW(sWih, EMB * 2, g * MSL + mt * 16 + lr, kb);
        acc[0][mt][g] = __builtin_amdgcn_mfma_f32_16x16x32_bf16(a0, bq, acc[0][mt][g], 0, 0, 0);
        acc[1][mt][g] = __builtin_amdgcn_mfma_f32_16x16x32_bf16(a1, bq, acc[1][mt][g], 0, 0, 0);
      }
    if (ms0) {
      short8 bqL = {0, 0, 0, 0, 0, 0, 0, 0};
      if (lr < 2) bqL = ldsW(sWcl, EMB * 2, lr, kb);
      accL[0] = __builtin_amdgcn_mfma_f32_16x16x32_bf16(a0, bqL, accL[0], 0, 0, 0);
      accL[1] = __builtin_amdgcn_mfma_f32_16x16x32_bf16(a1, bqL, accL[1], 0, 0, 0);
    }
    pa0 = na0; pb0 = nb0; pa1 = na1; pb1 = nb1;
  }

  // ---------------- GEMM2: H @ W_hh^T ----------------
#pragma unroll
  for (int kc = 0; kc < MEM / 32; ++kc) {
    const int kn = (kc < MEM / 32 - 1) ? kc + 1 : kc;
    f32x4 ra0 = *(const f32x4*)(h0 + kn * 32), rb0 = *(const f32x4*)(h0 + kn * 32 + 4);
    f32x4 ra1 = *(const f32x4*)(h1 + kn * 32), rb1 = *(const f32x4*)(h1 + kn * 32 + 4);
    const short8 a0 = cvt8(qa0, qb0);
    const short8 a1 = cvt8(qa1, qb1);
    const int kb = (kc * 32 + lk * 8) * 2;
#pragma unroll
    for (int mt = 0; mt < 2; ++mt) {
      const short8 b0 = ldsW(sWhh, MEM * 2, 0 * MSL + mt * 16 + lr, kb);
      const short8 b1 = ldsW(sWhh, MEM * 2, 1 * MSL + mt * 16 + lr, kb);
      const short8 b2 = ldsW(sWhh, MEM * 2, 2 * MSL + mt * 16 + lr, kb);
      acc[0][mt][0] = __builtin_amdgcn_mfma_f32_16x16x32_bf16(a0, b0, acc[0][mt][0], 0, 0, 0);
      acc[1][mt][0] = __builtin_amdgcn_mfma_f32_16x16x32_bf16(a1, b0, acc[1][mt][0], 0, 0, 0);
      acc[0][mt][1] = __builtin_amdgcn_mfma_f32_16x16x32_bf16(a0, b1, acc[0][mt][1], 0, 0, 0);
      acc[1][mt][1] = __builtin_amdgcn_mfma_f32_16x16x32_bf16(a1, b1, acc[1][mt][1], 0, 0, 0);
      accN[0][mt]   = __builtin_amdgcn_mfma_f32_16x16x32_bf16(a0, b2, accN[0][mt],   0, 0, 0);
      accN[1][mt]   = __builtin_amdgcn_mfma_f32_16x16x32_bf16(a1, b2, accN[1][mt],   0, 0, 0);
    }
    qa0 = ra0; qb0 = rb0; qa1 = ra1; qb1 = rb1;
  }

  // ---------------- GRU epilogue + scatter + logits ----------------
  float wcm0[2], wcm1[2], bir[2], bhr[2], biz[2], bhz[2], bin_[2], bhn[2];
#pragma unroll
  for (int mt = 0; mt < 2; ++mt) {
    const int m = ms * MSL + mt * 16 + lr;
    wcm0[mt] = Wcls[EMB + m];
    wcm1[mt] = Wcls[CLS_K + EMB + m];
    bir[mt] = bih[m];            bhr[mt] = bhh[m];
    biz[mt] = bih[MEM + m];      bhz[mt] = bhh[MEM + m];
    bin_[mt] = bih[2 * MEM + m]; bhn[mt] = bhh[2 * MEM + m];
  }

#pragma unroll
  for (int rt = 0; rt < 2; ++rt) {
#pragma unroll
    for (int j = 0; j < 4; ++j) {
      const int rowl = wrow + rt * 16 + lk * 4 + j;   // C/D: row=(lane>>4)*4+reg, col=lane&15
      const int grow = r0 + rowl;
      const bool valid = grow < N;
      const int gid = ids[valid ? grow : N - 1];
      float lp0 = 0.f, lp1 = 0.f;
#pragma unroll
      for (int mt = 0; mt < 2; ++mt) {
        const int m = ms * MSL + mt * 16 + lr;
        const float rg = sigm(acc[rt][mt][0][j] + bir[mt] + bhr[mt]);
        const float zg = sigm(acc[rt][mt][1][j] + biz[mt] + bhz[mt]);
        const float hn = accN[rt][mt][j] + bhn[mt];
        const float ng = tanhfast(acc[rt][mt][2][j] + bin_[mt] + rg * hn);
        const float hp = bank[(size_t)gid * MEM + m];
        const float nv = (1.f - zg) * ng + zg * hp;
        if (valid) out_bank[(size_t)gid * MEM + m] = nv;
        lp0 += nv * wcm0[mt];
        lp1 += nv * wcm1[mt];
      }
#pragma unroll
      for (int s = 1; s < 16; s <<= 1) {
        lp0 += __shfl_xor(lp0, s);
        lp1 += __shfl_xor(lp1, s);
      }
      if (valid && lr == 0) {
        atomicAdd(out_logits + (size_t)grow * 2 + 0, lp0);
        atomicAdd(out_logits + (size_t)grow * 2 + 1, lp1);
      }
      if (ms0 && valid && lr < 2) {
        atomicAdd(out_logits + (size_t)grow * 2 + lr, accL[rt][j] + bcls[lr]);
      }
    }
  }
}

extern "C" void kernel_launch(void* const* d_in, const int* in_sizes, int n_in,
                              void* d_out, int out_size, void* d_ws, size_t ws_size,
                              hipStream_t stream) {
  const float* emb  = (const float*)d_in[0];
  const int*   ids  = (const int*)d_in[1];
  const float* bank = (const float*)d_in[2];
  const float* wih  = (const float*)d_in[3];
  const float* whh  = (const float*)d_in[4];
  const float* bih  = (const float*)d_in[5];
  const float* bhh  = (const float*)d_in[6];
  const float* wcls = (const float*)d_in[7];
  const float* bcls = (const float*)d_in[8];

  const int N          = in_sizes[1];
  const int bank_elems = in_sizes[2];
  const int bank_rows  = bank_elems / MEM;
  const int n4         = bank_elems / 4;

  float* out_logits = (float*)d_out;
  float* out_bank   = (float*)d_out + (size_t)N * 2;

  const int wtot = G3 * EMB + G3 * MEM + 2 * CLS_K;
  const size_t wbytes = (size_t)wtot * sizeof(short);        // 494080, 4B-aligned
  const size_t bmbytes = (size_t)((bank_rows + 3) / 4) * 4;

  const bool haveW  = ws_size >= wbytes;
  const bool haveBM = ws_size >= wbytes + bmbytes;

  short* wb = (short*)d_ws;
  unsigned char* bm = (unsigned char*)d_ws + wbytes;
  u32* bmw = (u32*)bm;
  const int nbm = haveBM ? (int)(bmbytes / 4) : 0;

  // 1) zero logits (+ bitmap)
  {
    const int ntot = N * 2 + nbm;
    zero_kernel<<<(ntot + 255) / 256, 256, 0, stream>>>(out_logits, N * 2,
                                                        haveBM ? bmw : nullptr, nbm);
  }
  // 2) mark active rows, 3) copy non-active bank rows
  if (haveBM) {
    bitmap_set_kernel<<<(N + 255) / 256, 256, 0, stream>>>(ids, bm, N);
    copy_bank_kernel<<<4096, 256, 0, stream>>>((const f32x4*)bank, (f32x4*)out_bank, bm, n4);
  } else {
    copy_bank_kernel<<<4096, 256, 0, stream>>>((const f32x4*)bank, (f32x4*)out_bank, nullptr, n4);
  }

  const int nrb = (N + BR - 1) / BR;
  const int nb  = nrb * MSPLIT;
  if (haveW) {
    prep_w_kernel<<<(wtot + 255) / 256, 256, 0, stream>>>(wih, whh, wcls, wb);
    fused_gru_kernel<true><<<nb, NTHR, 0, stream>>>(emb, ids, bank, wih, whh, bih, bhh,
                                                    wcls, bcls, wb, out_logits, out_bank, N);
  } else {
    fused_gru_kernel<false><<<nb, NTHR, 0, stream>>>(emb, ids, bank, wih, whh, bih, bhh,
                                                     wcls, bcls, nullptr, out_logits, out_bank, N);
  }
}

// Round 4
// 411.620 us; speedup vs baseline: 1.6079x; 1.1242x over previous
//
#include <hip/hip_runtime.h>
#include <hip/hip_bf16.h>

typedef short short8 __attribute__((ext_vector_type(8)));
typedef float f32x4  __attribute__((ext_vector_type(4)));
typedef unsigned int u32;

#define EMB   512
#define MEM   128
#define G3    384
#define CLS_K 640
#define MSPLIT 4
#define MSL   32              // m-columns per block
#define BR    512             // rows per block (16 waves x 32)
#define NTHR  1024

#define W1ROWS 96             // 3 gates * MSL
#define SWIH_E (W1ROWS * EMB) // 49152 shorts
#define SWHH_E (W1ROWS * MEM) // 12288 shorts
#define SWCL_E (2 * EMB)      // 1024 shorts

__device__ __forceinline__ short f2b(float f) {
  __hip_bfloat16 h = __float2bfloat16(f);
  return __builtin_bit_cast(short, h);
}
__device__ __forceinline__ short8 cvt8(f32x4 a, f32x4 b) {
  short8 v;
  v[0] = f2b(a[0]); v[1] = f2b(a[1]); v[2] = f2b(a[2]); v[3] = f2b(a[3]);
  v[4] = f2b(b[0]); v[5] = f2b(b[1]); v[6] = f2b(b[2]); v[7] = f2b(b[3]);
  return v;
}
__device__ __forceinline__ float sigm(float x)     { return 1.f / (1.f + __expf(-x)); }
__device__ __forceinline__ float tanhfast(float x) { return 2.f / (1.f + __expf(-2.f * x)) - 1.f; }

// swizzled LDS access: spreads same-column reads across 8 16B slots
__device__ __forceinline__ short8 ldsW(const short* base, int rowBytes, int r, int kb) {
  const int byte = (r * rowBytes + kb) ^ ((r & 7) << 4);
  return *(const short8*)((const char*)base + byte);
}
__device__ __forceinline__ void stsW(short* base, int rowBytes, int r, int kb, short8 v) {
  const int byte = (r * rowBytes + kb) ^ ((r & 7) << 4);
  *(short8*)((char*)base + byte) = v;
}

// ---- convert all weights to bf16 in workspace ----
__global__ void prep_w_kernel(const float* __restrict__ wih, const float* __restrict__ whh,
                              const float* __restrict__ wcls, short* __restrict__ outw) {
  int i = blockIdx.x * blockDim.x + threadIdx.x;
  const int n1 = G3 * EMB;
  const int n2 = n1 + G3 * MEM;
  const int n3 = n2 + 2 * CLS_K;
  if (i < n1) outw[i] = f2b(wih[i]);
  else if (i < n2) outw[i] = f2b(whh[i - n1]);
  else if (i < n3) outw[i] = f2b(wcls[i - n2]);
}

// ---- zero logits + bitmap ----
__global__ void zero_kernel(float* __restrict__ lg, int nlg, u32* __restrict__ bm, int nbm) {
  int i = blockIdx.x * blockDim.x + threadIdx.x;
  int stride = gridDim.x * blockDim.x;
  for (; i < nlg + nbm; i += stride) {
    if (i < nlg) lg[i] = 0.f;
    else if (bm) bm[i - nlg] = 0u;
  }
}

__global__ void bitmap_set_kernel(const int* __restrict__ ids, unsigned char* __restrict__ bm, int n) {
  int i = blockIdx.x * blockDim.x + threadIdx.x;
  if (i < n) bm[ids[i]] = 1;
}

// ---- bank copy; skips rows the scatter will overwrite (bm!=null) ----
__global__ void copy_bank_kernel(const f32x4* __restrict__ src, f32x4* __restrict__ dst,
                                 const unsigned char* __restrict__ bm, int n4) {
  int i = blockIdx.x * blockDim.x + threadIdx.x;
  int stride = gridDim.x * blockDim.x;
  for (; i < n4; i += stride) {
    if (bm && bm[i >> 5]) continue;    // MEM/4 = 32 chunks per row
    dst[i] = src[i];
  }
}

template <bool BF16W>
__global__ __launch_bounds__(NTHR, 4)
void fused_gru_kernel(const float* __restrict__ emb, const int* __restrict__ ids,
                      const float* __restrict__ bank,
                      const float* __restrict__ Wihf, const float* __restrict__ Whhf,
                      const float* __restrict__ bih,  const float* __restrict__ bhh,
                      const float* __restrict__ Wcls, const float* __restrict__ bcls,
                      const short* __restrict__ Wb,
                      float* __restrict__ out_logits, float* __restrict__ out_bank, int N) {
  __shared__ __align__(16) short sW[SWIH_E + SWHH_E + SWCL_E];   // 122 KB
  short* sWih = sW;
  short* sWhh = sW + SWIH_E;
  short* sWcl = sW + SWIH_E + SWHH_E;

  const int t = threadIdx.x;

  // ---- block remap: all 4 m-slices of a row-group on the same XCD, dispatched together ----
  const int nrb   = (N + BR - 1) / BR;
  const int full  = nrb & ~7;
  const int nfull = full * 4;
  int rg, ms;
  {
    const int bi = blockIdx.x;
    if (bi < nfull) { rg = (bi & 7) + ((bi >> 5) << 3); ms = (bi >> 3) & 3; }
    else            { const int r = bi - nfull, rem = nrb - full; rg = full + r % rem; ms = r / rem; }
  }
  const bool ms0 = (ms == 0);
  const int r0 = rg * BR;

  // ---------------- per-wave setup + early gather issue ----------------
  const int w    = t >> 6;          // 0..15, wave owns rows [w*32, w*32+32)
  const int l    = t & 63;
  const int lr   = l & 15;
  const int lk   = l >> 4;
  const int wrow = w * 32;

  int grow0 = r0 + wrow + lr;      if (grow0 > N - 1) grow0 = N - 1;
  int grow1 = r0 + wrow + 16 + lr; if (grow1 > N - 1) grow1 = N - 1;
  const int gid0 = ids[grow0];
  const int gid1 = ids[grow1];

  const float* x0 = emb  + (size_t)grow0 * EMB + lk * 8;
  const float* x1 = emb  + (size_t)grow1 * EMB + lk * 8;
  const float* h0 = bank + (size_t)gid0 * MEM + lk * 8;
  const float* h1 = bank + (size_t)gid1 * MEM + lk * 8;

  // issue GEMM2's first A-loads and GEMM1's first A-loads before weight staging
  f32x4 qa0 = *(const f32x4*)h0, qb0 = *(const f32x4*)(h0 + 4);
  f32x4 qa1 = *(const f32x4*)h1, qb1 = *(const f32x4*)(h1 + 4);
  f32x4 pa0 = *(const f32x4*)x0, pb0 = *(const f32x4*)(x0 + 4);
  f32x4 pa1 = *(const f32x4*)x1, pb1 = *(const f32x4*)(x1 + 4);

  const short* Wihb = Wb;
  const short* Whhb = Wb + G3 * EMB;
  const short* Wclb = Wb + G3 * EMB + G3 * MEM;

  // ---------------- stage weight slices into swizzled LDS ----------------
  // local row r in [0,96): gate g=r/32, mloc=r%32 -> global row g*128 + ms*32 + mloc
#pragma unroll
  for (int i = 0; i < 6; ++i) {                     // W_ih: 6144 16B chunks
    const int c = t + i * NTHR;
    const int r = c >> 6, k8 = c & 63;
    const int grow = (r >> 5) * MEM + ms * MSL + (r & 31);
    short8 v;
    if constexpr (BF16W) v = *(const short8*)(Wihb + (size_t)grow * EMB + k8 * 8);
    else {
      const float* p = Wihf + (size_t)grow * EMB + k8 * 8;
      v = cvt8(*(const f32x4*)p, *(const f32x4*)(p + 4));
    }
    stsW(sWih, EMB * 2, r, k8 * 16, v);
  }
#pragma unroll
  for (int i = 0; i < 2; ++i) {                     // W_hh: 1536 16B chunks
    const int c = t + i * NTHR;
    if (c < 1536) {
      const int r = c >> 4, k8 = c & 15;
      const int grow = (r >> 5) * MEM + ms * MSL + (r & 31);
      short8 v;
      if constexpr (BF16W) v = *(const short8*)(Whhb + (size_t)grow * MEM + k8 * 8);
      else {
        const float* p = Whhf + (size_t)grow * MEM + k8 * 8;
        v = cvt8(*(const f32x4*)p, *(const f32x4*)(p + 4));
      }
      stsW(sWhh, MEM * 2, r, k8 * 16, v);
    }
  }
  if (t < 128) {                                    // W_cls emb-part: 2 rows x 512
    const int r = t >> 6, k8 = t & 63;
    short8 v;
    if constexpr (BF16W) v = *(const short8*)(Wclb + (size_t)r * CLS_K + k8 * 8);
    else {
      const float* p = Wcls + (size_t)r * CLS_K + k8 * 8;
      v = cvt8(*(const f32x4*)p, *(const f32x4*)(p + 4));
    }
    stsW(sWcl, EMB * 2, r, k8 * 16, v);
  }
  __syncthreads();

  f32x4 acc[2][2][3];   // [rowtile][mtile][gate0=r, gate1=z, gate2=i_n]
  f32x4 accN[2][2];     // h_n
  f32x4 accL[2];        // emb-part logits (ms==0 only)
  const f32x4 zero = {0.f, 0.f, 0.f, 0.f};
#pragma unroll
  for (int rt = 0; rt < 2; ++rt) {
#pragma unroll
    for (int mt = 0; mt < 2; ++mt) {
#pragma unroll
      for (int g = 0; g < 3; ++g) acc[rt][mt][g] = zero;
      accN[rt][mt] = zero;
    }
    accL[rt] = zero;
  }

  // ---------------- GEMM1: X @ W_ih^T (B from LDS, A prefetched) ----------------
#pragma unroll 4
  for (int kc = 0; kc < EMB / 32; ++kc) {
    const int kn = (kc < EMB / 32 - 1) ? kc + 1 : kc;
    f32x4 na0 = *(const f32x4*)(x0 + kn * 32), nb0 = *(const f32x4*)(x0 + kn * 32 + 4);
    f32x4 na1 = *(const f32x4*)(x1 + kn * 32), nb1 = *(const f32x4*)(x1 + kn * 32 + 4);
    const short8 a0 = cvt8(pa0, pb0);
    const short8 a1 = cvt8(pa1, pb1);
    const int kb = (kc * 32 + lk * 8) * 2;
#pragma unroll
    for (int g = 0; g < 3; ++g)
#pragma unroll
      for (int mt = 0; mt < 2; ++mt) {
        const short8 bq = ldsW(sWih, EMB * 2, g * MSL + mt * 16 + lr, kb);
        acc[0][mt][g] = __builtin_amdgcn_mfma_f32_16x16x32_bf16(a0, bq, acc[0][mt][g], 0, 0, 0);
        acc[1][mt][g] = __builtin_amdgcn_mfma_f32_16x16x32_bf16(a1, bq, acc[1][mt][g], 0, 0, 0);
      }
    if (ms0) {
      short8 bqL = {0, 0, 0, 0, 0, 0, 0, 0};
      if (lr < 2) bqL = ldsW(sWcl, EMB * 2, lr, kb);
      accL[0] = __builtin_amdgcn_mfma_f32_16x16x32_bf16(a0, bqL, accL[0], 0, 0, 0);
      accL[1] = __builtin_amdgcn_mfma_f32_16x16x32_bf16(a1, bqL, accL[1], 0, 0, 0);
    }
    pa0 = na0; pb0 = nb0; pa1 = na1; pb1 = nb1;
  }

  // ---------------- GEMM2: H @ W_hh^T ----------------
#pragma unroll
  for (int kc = 0; kc < MEM / 32; ++kc) {
    const int kn = (kc < MEM / 32 - 1) ? kc + 1 : kc;
    f32x4 ra0 = *(const f32x4*)(h0 + kn * 32), rb0 = *(const f32x4*)(h0 + kn * 32 + 4);
    f32x4 ra1 = *(const f32x4*)(h1 + kn * 32), rb1 = *(const f32x4*)(h1 + kn * 32 + 4);
    const short8 a0 = cvt8(qa0, qb0);
    const short8 a1 = cvt8(qa1, qb1);
    const int kb = (kc * 32 + lk * 8) * 2;
#pragma unroll
    for (int mt = 0; mt < 2; ++mt) {
      const short8 b0 = ldsW(sWhh, MEM * 2, 0 * MSL + mt * 16 + lr, kb);
      const short8 b1 = ldsW(sWhh, MEM * 2, 1 * MSL + mt * 16 + lr, kb);
      const short8 b2 = ldsW(sWhh, MEM * 2, 2 * MSL + mt * 16 + lr, kb);
      acc[0][mt][0] = __builtin_amdgcn_mfma_f32_16x16x32_bf16(a0, b0, acc[0][mt][0], 0, 0, 0);
      acc[1][mt][0] = __builtin_amdgcn_mfma_f32_16x16x32_bf16(a1, b0, acc[1][mt][0], 0, 0, 0);
      acc[0][mt][1] = __builtin_amdgcn_mfma_f32_16x16x32_bf16(a0, b1, acc[0][mt][1], 0, 0, 0);
      acc[1][mt][1] = __builtin_amdgcn_mfma_f32_16x16x32_bf16(a1, b1, acc[1][mt][1], 0, 0, 0);
      accN[0][mt]   = __builtin_amdgcn_mfma_f32_16x16x32_bf16(a0, b2, accN[0][mt],   0, 0, 0);
      accN[1][mt]   = __builtin_amdgcn_mfma_f32_16x16x32_bf16(a1, b2, accN[1][mt],   0, 0, 0);
    }
    qa0 = ra0; qb0 = rb0; qa1 = ra1; qb1 = rb1;
  }

  // ---------------- GRU epilogue + scatter + logits ----------------
  float wcm0[2], wcm1[2], bir[2], bhr[2], biz[2], bhz[2], bin_[2], bhn[2];
#pragma unroll
  for (int mt = 0; mt < 2; ++mt) {
    const int m = ms * MSL + mt * 16 + lr;
    wcm0[mt] = Wcls[EMB + m];
    wcm1[mt] = Wcls[CLS_K + EMB + m];
    bir[mt] = bih[m];            bhr[mt] = bhh[m];
    biz[mt] = bih[MEM + m];      bhz[mt] = bhh[MEM + m];
    bin_[mt] = bih[2 * MEM + m]; bhn[mt] = bhh[2 * MEM + m];
  }

#pragma unroll
  for (int rt = 0; rt < 2; ++rt) {
#pragma unroll
    for (int j = 0; j < 4; ++j) {
      const int rowl = wrow + rt * 16 + lk * 4 + j;   // C/D: row=(lane>>4)*4+reg, col=lane&15
      const int grow = r0 + rowl;
      const bool valid = grow < N;
      const int gid = __shfl(rt ? gid1 : gid0, lk * 4 + j);   // ids for this C-row
      float lp0 = 0.f, lp1 = 0.f;
#pragma unroll
      for (int mt = 0; mt < 2; ++mt) {
        const int m = ms * MSL + mt * 16 + lr;
        const float rg_ = sigm(acc[rt][mt][0][j] + bir[mt] + bhr[mt]);
        const float zg  = sigm(acc[rt][mt][1][j] + biz[mt] + bhz[mt]);
        const float hn  = accN[rt][mt][j] + bhn[mt];
        const float ng  = tanhfast(acc[rt][mt][2][j] + bin_[mt] + rg_ * hn);
        const float hp  = bank[(size_t)gid * MEM + m];
        const float nv  = (1.f - zg) * ng + zg * hp;
        if (valid) out_bank[(size_t)gid * MEM + m] = nv;
        lp0 += nv * wcm0[mt];
        lp1 += nv * wcm1[mt];
      }
#pragma unroll
      for (int s = 1; s < 16; s <<= 1) {
        lp0 += __shfl_xor(lp0, s);
        lp1 += __shfl_xor(lp1, s);
      }
      if (valid && lr == 0) {
        atomicAdd(out_logits + (size_t)grow * 2 + 0, lp0);
        atomicAdd(out_logits + (size_t)grow * 2 + 1, lp1);
      }
      if (ms0 && valid && lr < 2) {
        atomicAdd(out_logits + (size_t)grow * 2 + lr, accL[rt][j] + bcls[lr]);
      }
    }
  }
}

extern "C" void kernel_launch(void* const* d_in, const int* in_sizes, int n_in,
                              void* d_out, int out_size, void* d_ws, size_t ws_size,
                              hipStream_t stream) {
  const float* emb  = (const float*)d_in[0];
  const int*   ids  = (const int*)d_in[1];
  const float* bank = (const float*)d_in[2];
  const float* wih  = (const float*)d_in[3];
  const float* whh  = (const float*)d_in[4];
  const float* bih  = (const float*)d_in[5];
  const float* bhh  = (const float*)d_in[6];
  const float* wcls = (const float*)d_in[7];
  const float* bcls = (const float*)d_in[8];

  const int N          = in_sizes[1];
  const int bank_elems = in_sizes[2];
  const int bank_rows  = bank_elems / MEM;
  const int n4         = bank_elems / 4;

  float* out_logits = (float*)d_out;
  float* out_bank   = (float*)d_out + (size_t)N * 2;

  const int wtot = G3 * EMB + G3 * MEM + 2 * CLS_K;
  const size_t wbytes = (size_t)wtot * sizeof(short);        // 494080, 4B-aligned
  const size_t bmbytes = (size_t)((bank_rows + 3) / 4) * 4;

  const bool haveW  = ws_size >= wbytes;
  const bool haveBM = ws_size >= wbytes + bmbytes;

  short* wb = (short*)d_ws;
  unsigned char* bm = (unsigned char*)d_ws + wbytes;
  u32* bmw = (u32*)bm;
  const int nbm = haveBM ? (int)(bmbytes / 4) : 0;

  // 1) zero logits (+ bitmap)
  {
    const int ntot = N * 2 + nbm;
    zero_kernel<<<(ntot + 255) / 256, 256, 0, stream>>>(out_logits, N * 2,
                                                        haveBM ? bmw : nullptr, nbm);
  }
  // 2) mark active rows, 3) copy non-active bank rows
  if (haveBM) {
    bitmap_set_kernel<<<(N + 255) / 256, 256, 0, stream>>>(ids, bm, N);
    copy_bank_kernel<<<4096, 256, 0, stream>>>((const f32x4*)bank, (f32x4*)out_bank, bm, n4);
  } else {
    copy_bank_kernel<<<4096, 256, 0, stream>>>((const f32x4*)bank, (f32x4*)out_bank, nullptr, n4);
  }

  const int nrb = (N + BR - 1) / BR;
  const int nb  = nrb * MSPLIT;
  if (haveW) {
    prep_w_kernel<<<(wtot + 255) / 256, 256, 0, stream>>>(wih, whh, wcls, wb);
    fused_gru_kernel<true><<<nb, NTHR, 0, stream>>>(emb, ids, bank, wih, whh, bih, bhh,
                                                    wcls, bcls, wb, out_logits, out_bank, N);
  } else {
    fused_gru_kernel<false><<<nb, NTHR, 0, stream>>>(emb, ids, bank, wih, whh, bih, bhh,
                                                     wcls, bcls, nullptr, out_logits, out_bank, N);
  }
}